// Round 12
// baseline (31.524 us; speedup 1.0000x reference)
//
#include <hip/hip_runtime.h>

typedef float v4f __attribute__((ext_vector_type(4)));

#define BLK 256
#define IPT 4                 // i-particles per thread
#define TI (BLK * IPT)        // 1024 i's per block
#define TJ 64                 // j's staged per block
#define JBT (TI / TJ)         // 16 j-blocks per i-tile
#define G_CONST 0.001f
#define EPS_CONST 1e-6f

// Triangular at (1024 x 64): 62.5% of full work. 1280 blocks, bounds(256,5)
// -> exactly 5 resident blocks/CU, no tail round.
// Inner loop is PHASE-BATCHED to force ILP: 16 r^2 chains live at once
// (t[] array, static indices), then 16 back-to-back v_rsq (pipelined trans),
// then diag-mask, then 4 independent accumulator chains. R10's VGPR=16 proved
// the compiler otherwise serializes the per-pair chain (ILP=1 -> 62% stall).
__global__ __launch_bounds__(BLK, 5)
void grav_kernel(const float* __restrict__ q, const float* __restrict__ m,
                 float* __restrict__ out, int N) {
  const int b   = blockIdx.z;
  const int tid = threadIdx.x;

  // Decode blockIdx.x -> (i-tile a, j-block jt); i-tile a owns JBT*(a+1) blocks.
  int rel = blockIdx.x;
  int a = 0;
  while (rel >= JBT * (a + 1)) { rel -= JBT * (a + 1); ++a; }
  const int jt   = rel;
  const bool diag = (jt >= JBT * a);
  const int i0 = a * TI;
  const int j0 = jt * TJ;

  __shared__ float xs[TJ], ys[TJ], zs[TJ], sjs[TJ], ms[TJ];
  __shared__ float wsum[4];

  const float* qb = q + (size_t)b * N * 3;

  // Stage j tile: coords, |qj|^2, mass (SoA -> broadcast ds_read_b128).
  if (tid < TJ) {
    const int j = j0 + tid;
    const float x = qb[3 * j + 0];
    const float y = qb[3 * j + 1];
    const float z = qb[3 * j + 2];
    xs[tid]  = x;
    ys[tid]  = y;
    zs[tid]  = z;
    sjs[tid] = fmaf(x, x, fmaf(y, y, z * z));
    ms[tid]  = m[j];
  }

  // Per-thread i-state: -2*coords (expansion form), |qi|^2+eps, mass.
  float txi[IPT], tyi[IPT], tzi[IPT], se[IPT], mi[IPT];
#pragma unroll
  for (int s = 0; s < IPT; ++s) {
    const int i = i0 + s * BLK + tid;
    const float x = qb[3 * i + 0];
    const float y = qb[3 * i + 1];
    const float z = qb[3 * i + 2];
    txi[s] = -2.f * x;
    tyi[s] = -2.f * y;
    tzi[s] = -2.f * z;
    se[s]  = fmaf(x, x, fmaf(y, y, fmaf(z, z, EPS_CONST)));
    mi[s]  = m[i];
  }

  __syncthreads();

  float acc[IPT] = {};

#pragma unroll 2
  for (int k = 0; k < TJ; k += 4) {
    const v4f xj = *(const v4f*)&xs[k];
    const v4f yj = *(const v4f*)&ys[k];
    const v4f zj = *(const v4f*)&zs[k];
    const v4f sj = *(const v4f*)&sjs[k];
    const v4f mj = *(const v4f*)&ms[k];

    // Phase A: 16 independent r^2 chains (all live -> compiler must allocate).
    float t[IPT][4];
#pragma unroll
    for (int s = 0; s < IPT; ++s)
#pragma unroll
      for (int u = 0; u < 4; ++u) {
        float tt = se[s] + sj[u];
        tt = fmaf(txi[s], xj[u], tt);
        tt = fmaf(tyi[s], yj[u], tt);
        tt = fmaf(tzi[s], zj[u], tt);
        t[s][u] = tt;
      }

    // Phase B: 16 back-to-back rsq -> trans pipe stays saturated.
    float r[IPT][4];
#pragma unroll
    for (int s = 0; s < IPT; ++s)
#pragma unroll
      for (int u = 0; u < 4; ++u)
        r[s][u] = __builtin_amdgcn_rsqf(t[s][u]);

    // Phase C (diag only): mask self-pairs (t ~ eps +/- rounding; may be <=0
    // -> NaN from rsq; cndmask AFTER rsq kills it, matching diagonal-zeroing).
    if (diag) {
#pragma unroll
      for (int s = 0; s < IPT; ++s) {
        const int i = i0 + s * BLK + tid;
#pragma unroll
        for (int u = 0; u < 4; ++u)
          r[s][u] = (i == j0 + k + u) ? 0.f : r[s][u];
      }
    }

    // Phase D: 4 independent accumulator chains.
#pragma unroll
    for (int s = 0; s < IPT; ++s)
#pragma unroll
      for (int u = 0; u < 4; ++u)
        acc[s] = fmaf(mj[u], r[s][u], acc[s]);
  }

  float tsum = 0.f;
#pragma unroll
  for (int s = 0; s < IPT; ++s) tsum += mi[s] * acc[s];

  // Block reduction: 64-lane shuffle, then across 4 waves via LDS.
#pragma unroll
  for (int off = 32; off > 0; off >>= 1) tsum += __shfl_down(tsum, off);
  const int wid  = tid >> 6;
  const int lane = tid & 63;
  if (lane == 0) wsum[wid] = tsum;
  __syncthreads();
  if (tid == 0) {
    const float s = (wsum[0] + wsum[1]) + (wsum[2] + wsum[3]);
    // off-diag: each unordered pair once -> -G; diag: both orders -> -G/2.
    const float scale = diag ? (-0.5f * G_CONST) : (-G_CONST);
    atomicAdd(out + b, s * scale);
  }
}

extern "C" void kernel_launch(void* const* d_in, const int* in_sizes, int n_in,
                              void* d_out, int out_size, void* d_ws, size_t ws_size,
                              hipStream_t stream) {
  const float* q = (const float*)d_in[0];
  const float* m = (const float*)d_in[1];
  float* out = (float*)d_out;

  const int N = in_sizes[1];
  const int B = in_sizes[0] / (N * 3);

  hipMemsetAsync(out, 0, (size_t)out_size * sizeof(float), stream);

  const int nti = N / TI;                      // 4 i-tiles
  const int bpb = JBT * nti * (nti + 1) / 2;   // 160 blocks per batch
  dim3 grid(bpb, 1, B);                        // 1280 blocks = 5/CU exactly
  grav_kernel<<<grid, BLK, 0, stream>>>(q, m, out, N);
}